// Round 2
// baseline (787.349 us; speedup 1.0000x reference)
//
#include <hip/hip_runtime.h>

typedef unsigned short u16;
typedef __bf16 bf16x8 __attribute__((ext_vector_type(8)));
typedef unsigned short u16x8 __attribute__((ext_vector_type(8)));
typedef float f32x4 __attribute__((ext_vector_type(4)));

#define GLDS16(gp, lp)                                                        \
  __builtin_amdgcn_global_load_lds(                                           \
      (const __attribute__((address_space(1))) void*)(gp),                    \
      (__attribute__((address_space(3))) void*)(lp), 16, 0, 0)

__device__ __forceinline__ u16 f2bf(float f) {
  unsigned u = __float_as_uint(f);
  u += 0x7FFFu + ((u >> 16) & 1u);
  return (u16)(u >> 16);
}

__device__ __forceinline__ f32x4 mfma_bf16(bf16x8 a, bf16x8 b, f32x4 c) {
  return __builtin_amdgcn_mfma_f32_16x16x32_bf16(a, b, c, 0, 0, 0);
}

// ---------------------------------------------------------------- convert
__global__ void cvt_f32_bf16(const float* __restrict__ src,
                             u16* __restrict__ dst, int n8) {
  for (int i = blockIdx.x * blockDim.x + threadIdx.x; i < n8;
       i += gridDim.x * blockDim.x) {
    const float4* sp = (const float4*)src + (size_t)i * 2;
    float4 a = sp[0], b = sp[1];
    u16x8 o;
    o[0] = f2bf(a.x); o[1] = f2bf(a.y); o[2] = f2bf(a.z); o[3] = f2bf(a.w);
    o[4] = f2bf(b.x); o[5] = f2bf(b.y); o[6] = f2bf(b.z); o[7] = f2bf(b.w);
    *((u16x8*)dst + i) = o;
  }
}

// ------------------------------------------------------------------- GEMM
// C[M][N] = A[M][K] * B[N][K]^T + bias[N].  (unchanged from round 0)
template <int OUT_BF16>
__global__ __launch_bounds__(256) void gemm_bt(const u16* __restrict__ A,
                                               const u16* __restrict__ B,
                                               const float* __restrict__ bias,
                                               void* __restrict__ Cout, int M,
                                               int N, int K) {
  __shared__ __attribute__((aligned(16))) u16 As[128 * 64];
  __shared__ __attribute__((aligned(16))) u16 Bs[128 * 64];
  const int t = threadIdx.x, lane = t & 63, w = t >> 6;
  const int l15 = lane & 15, l4 = lane >> 4;
  const int bm = blockIdx.x * 128, bn = blockIdx.y * 128;
  const int wr = (w >> 1) * 64, wc = (w & 1) * 64;

  f32x4 z4 = {0.f, 0.f, 0.f, 0.f};
  f32x4 acc[4][4];
#pragma unroll
  for (int i = 0; i < 4; ++i)
#pragma unroll
    for (int j = 0; j < 4; ++j) acc[i][j] = z4;

  const int srow = t >> 3;
  const int scol = ((t & 7) ^ (srow & 7)) << 3;
  const u16* Ag = A + (size_t)(bm + srow) * K + scol;
  const u16* Bg = B + (size_t)(bn + srow) * K + scol;
  u16* AsW = As + w * 512;
  u16* BsW = Bs + w * 512;

  for (int k0 = 0; k0 < K; k0 += 64) {
    __syncthreads();
#pragma unroll
    for (int i = 0; i < 4; ++i) {
      GLDS16(Ag + k0 + i * 32 * K, AsW + i * 2048);
      GLDS16(Bg + k0 + i * 32 * K, BsW + i * 2048);
    }
    __syncthreads();
#pragma unroll
    for (int kc = 0; kc < 2; ++kc) {
      bf16x8 af[4], bf[4];
#pragma unroll
      for (int x = 0; x < 4; ++x) {
        int ra = wr + x * 16 + l15;
        af[x] = *(const bf16x8*)(As + ra * 64 + (((kc * 4 + l4) ^ (ra & 7)) << 3));
        int rb = wc + x * 16 + l15;
        bf[x] = *(const bf16x8*)(Bs + rb * 64 + (((kc * 4 + l4) ^ (rb & 7)) << 3));
      }
#pragma unroll
      for (int mi = 0; mi < 4; ++mi)
#pragma unroll
        for (int ni = 0; ni < 4; ++ni)
          acc[mi][ni] = mfma_bf16(af[mi], bf[ni], acc[mi][ni]);
    }
  }
  const int cr = l4 * 4, cc = l15;
#pragma unroll
  for (int ni = 0; ni < 4; ++ni) {
    int col = bn + wc + ni * 16 + cc;
    float bv = bias[col];
#pragma unroll
    for (int mi = 0; mi < 4; ++mi)
#pragma unroll
      for (int r = 0; r < 4; ++r) {
        int row = bm + wr + mi * 16 + cr + r;
        float v = acc[mi][ni][r] + bv;
        if (OUT_BF16)
          ((u16*)Cout)[(size_t)row * N + col] = f2bf(v);
        else
          ((float*)Cout)[(size_t)row * N + col] = v;
      }
  }
}

// -------------------------------------------------------------- attention
// XOR-swizzled LDS index helpers (write and read both register-side).
__device__ __forceinline__ int vt_idx(int d, int kk) {
  return d * 64 + ((((kk >> 3) ^ ((d >> 3) & 7)) << 3) | (kk & 7));
}
__device__ __forceinline__ int ps_idx(int r, int c) {
  return r * 64 + ((((c >> 3) ^ ((r >> 2) & 7)) << 3) | (c & 7));
}

__global__ __launch_bounds__(256) void attn_fwd(const u16* __restrict__ qkv,
                                                u16* __restrict__ ctx) {
  constexpr int NQ = 6144, SD = 2048;
  __shared__ __attribute__((aligned(16))) u16 Ks[64 * 128];  // [kk][d] swz
  __shared__ __attribute__((aligned(16))) u16 Vt[128 * 64];  // [d][kk] swz
  __shared__ __attribute__((aligned(16))) u16 Ps[64 * 64];   // [q][kk] swz
  const int t = threadIdx.x, lane = t & 63, w = t >> 6;
  const int l15 = lane & 15, l4 = lane >> 4;
  const int q0 = (int)(gridDim.x - 1 - blockIdx.x) * 64;  // heavy blocks first
  const int h = blockIdx.y, b = blockIdx.z;
  const size_t rowbase = (size_t)b * SD;
  const int hq = h * 384;

  // Q fragments (raw, no prescale): A-layout row=l&15, k=(l>>4)*8+e per chunk
  bf16x8 qf[4];
  {
    const u16* qp = qkv + (rowbase + q0 + w * 16 + l15) * NQ + hq + l4 * 8;
#pragma unroll
    for (int kc = 0; kc < 4; ++kc) qf[kc] = *(const bf16x8*)(qp + kc * 32);
  }

  f32x4 z4 = {0.f, 0.f, 0.f, 0.f};
  f32x4 oacc[8];
#pragma unroll
  for (int i = 0; i < 8; ++i) oacc[i] = z4;
  float m_run[4], l_run[4];
#pragma unroll
  for (int r = 0; r < 4; ++r) { m_run[r] = -3.0e38f; l_run[r] = 0.f; }

  const u16* Kg = qkv + (rowbase + (t >> 4)) * NQ + hq + 128 +
                  (((t & 15) ^ ((t >> 4) & 7)) << 3);
  const u16* Vg = qkv + (rowbase + (t & 15)) * NQ + hq + 256 + ((t >> 4) << 3);
  const int vkk = t & 15, vd0 = (t >> 4) << 3;

  const float C = 0.12751879522447905f;  // (1/sqrt(128)) * log2(e)
  const float THRC = 8.0f / 0.12751879522447905f;  // defer-max threshold (raw)
  const int qrow = q0 + w * 16 + l4 * 4;  // + r

  for (int k0 = 0; k0 <= q0; k0 += 64) {
    __syncthreads();
#pragma unroll
    for (int i = 0; i < 4; ++i)
      GLDS16(Kg + (size_t)(k0 + i * 16) * NQ, Ks + i * 2048 + w * 512);
#pragma unroll
    for (int p = 0; p < 4; ++p) {
      u16x8 v = *(const u16x8*)(Vg + (size_t)(k0 + p * 16) * NQ);
      int kk = p * 16 + vkk;
#pragma unroll
      for (int j = 0; j < 8; ++j) Vt[vt_idx(vd0 + j, kk)] = v[j];
    }
    __syncthreads();

    // S = Q K^T (raw logits)
    f32x4 sc[4];
#pragma unroll
    for (int nf = 0; nf < 4; ++nf) sc[nf] = z4;
#pragma unroll
    for (int kc = 0; kc < 4; ++kc)
#pragma unroll
      for (int nf = 0; nf < 4; ++nf) {
        int rk = nf * 16 + l15;
        bf16x8 kf =
            *(const bf16x8*)(Ks + rk * 128 + (((kc * 4 + l4) ^ (rk & 7)) << 3));
        sc[nf] = mfma_bf16(qf[kc], kf, sc[nf]);
      }
    // causal mask: only the diagonal tile is partial
    if (k0 == q0) {
#pragma unroll
      for (int nf = 0; nf < 4; ++nf) {
        int col = k0 + nf * 16 + l15;
#pragma unroll
        for (int r = 0; r < 4; ++r)
          if (col > qrow + r) sc[nf][r] = -3.0e38f;
      }
    }
    // row max across the 16 col-lanes
    float mx[4];
#pragma unroll
    for (int r = 0; r < 4; ++r)
      mx[r] = fmaxf(fmaxf(sc[0][r], sc[1][r]), fmaxf(sc[2][r], sc[3][r]));
#pragma unroll
    for (int off = 8; off >= 1; off >>= 1)
#pragma unroll
      for (int r = 0; r < 4; ++r) mx[r] = fmaxf(mx[r], __shfl_xor(mx[r], off));
    // defer-max: rescale only if some row grew past threshold
    bool upd = false;
#pragma unroll
    for (int r = 0; r < 4; ++r) upd |= (mx[r] > m_run[r] + THRC);
    if (__any(upd)) {
#pragma unroll
      for (int r = 0; r < 4; ++r) {
        float mn = fmaxf(m_run[r], mx[r]);
        float cr = exp2f((m_run[r] - mn) * C);
        m_run[r] = mn;
        l_run[r] *= cr;
#pragma unroll
        for (int nf = 0; nf < 8; ++nf) oacc[nf][r] *= cr;
      }
    }
    float mC[4], sm[4];
#pragma unroll
    for (int r = 0; r < 4; ++r) mC[r] = m_run[r] * C;
    // P = exp2(S*C - m*C), write to Ps (bf16), accumulate row sums
#pragma unroll
    for (int nf = 0; nf < 4; ++nf)
#pragma unroll
      for (int r = 0; r < 4; ++r)
        sc[nf][r] = exp2f(fmaf(sc[nf][r], C, -mC[r]));
#pragma unroll
    for (int r = 0; r < 4; ++r)
      sm[r] = (sc[0][r] + sc[1][r]) + (sc[2][r] + sc[3][r]);
#pragma unroll
    for (int off = 8; off >= 1; off >>= 1)
#pragma unroll
      for (int r = 0; r < 4; ++r) sm[r] += __shfl_xor(sm[r], off);
#pragma unroll
    for (int r = 0; r < 4; ++r) l_run[r] += sm[r];
#pragma unroll
    for (int nf = 0; nf < 4; ++nf)
#pragma unroll
      for (int r = 0; r < 4; ++r)
        ((__bf16*)Ps)[ps_idx(w * 16 + l4 * 4 + r, nf * 16 + l15)] =
            (__bf16)sc[nf][r];
    // O += P V  (same-wave Ps write->read; Vt guarded by the mid barrier)
#pragma unroll
    for (int kc = 0; kc < 2; ++kc) {
      bf16x8 pf = *(const bf16x8*)(
          Ps + ps_idx(w * 16 + l15, kc * 32 + l4 * 8));
#pragma unroll
      for (int nf = 0; nf < 8; ++nf) {
        bf16x8 vf =
            *(const bf16x8*)(Vt + vt_idx(nf * 16 + l15, kc * 32 + l4 * 8));
        oacc[nf] = mfma_bf16(pf, vf, oacc[nf]);
      }
    }
  }
  // normalize + store ctx
  float inv[4];
#pragma unroll
  for (int r = 0; r < 4; ++r) inv[r] = 1.f / l_run[r];
  u16* cp = ctx + (rowbase + q0 + w * 16 + l4 * 4) * SD + h * 128 + l15;
#pragma unroll
  for (int nf = 0; nf < 8; ++nf)
#pragma unroll
    for (int r = 0; r < 4; ++r)
      ((__bf16*)cp)[(size_t)r * SD + nf * 16] = (__bf16)(oacc[nf][r] * inv[r]);
}

// ----------------------------------------------------------------- launch
extern "C" void kernel_launch(void* const* d_in, const int* in_sizes, int n_in,
                              void* d_out, int out_size, void* d_ws,
                              size_t ws_size, hipStream_t stream) {
  const float* x = (const float*)d_in[0];
  const float* wqkv = (const float*)d_in[2];
  const float* bqkv = (const float*)d_in[3];
  const float* wout = (const float*)d_in[4];
  const float* bout = (const float*)d_in[5];
  float* out = (float*)d_out;
  char* ws = (char*)d_ws;

  u16* xb = (u16*)(ws);                  //  33,554,432  x bf16 (later: ctx)
  u16* wqkvb = (u16*)(ws + 33554432);    //  25,165,824  w_qkv bf16
  u16* woutb = (u16*)(ws + 58720256);    //   8,388,608  w_out bf16
  u16* qkvb = (u16*)(ws + 67108864);     // 100,663,296  qkv bf16
  u16* ctx = xb;                         // reuse (x dead after gemm1)

  cvt_f32_bf16<<<2048, 256, 0, stream>>>(x, xb, 16777216 / 8);
  cvt_f32_bf16<<<2048, 256, 0, stream>>>(wqkv, wqkvb, 12582912 / 8);
  cvt_f32_bf16<<<1024, 256, 0, stream>>>(wout, woutb, 4194304 / 8);
  gemm_bt<1><<<dim3(64, 48), 256, 0, stream>>>(xb, wqkvb, bqkv, qkvb, 8192,
                                               6144, 2048);
  attn_fwd<<<dim3(32, 16, 4), 256, 0, stream>>>(qkvb, ctx);
  gemm_bt<0><<<dim3(64, 16), 256, 0, stream>>>(ctx, woutb, bout, out, 8192,
                                               2048, 2048);
}

// Round 3
// 705.539 us; speedup vs baseline: 1.1160x; 1.1160x over previous
//
#include <hip/hip_runtime.h>

typedef unsigned short u16;
typedef __bf16 bf16x8 __attribute__((ext_vector_type(8)));
typedef unsigned short u16x8 __attribute__((ext_vector_type(8)));
typedef float f32x4 __attribute__((ext_vector_type(4)));

#define GLDS16(gp, lp)                                                        \
  __builtin_amdgcn_global_load_lds(                                           \
      (const __attribute__((address_space(1))) void*)(gp),                    \
      (__attribute__((address_space(3))) void*)(lp), 16, 0, 0)

__device__ __forceinline__ u16 f2bf(float f) {
  unsigned u = __float_as_uint(f);
  u += 0x7FFFu + ((u >> 16) & 1u);
  return (u16)(u >> 16);
}

__device__ __forceinline__ f32x4 mfma_bf16(bf16x8 a, bf16x8 b, f32x4 c) {
  return __builtin_amdgcn_mfma_f32_16x16x32_bf16(a, b, c, 0, 0, 0);
}

// ---------------------------------------------------------------- convert
__global__ void cvt_f32_bf16(const float* __restrict__ src,
                             u16* __restrict__ dst, int n8) {
  for (int i = blockIdx.x * blockDim.x + threadIdx.x; i < n8;
       i += gridDim.x * blockDim.x) {
    const float4* sp = (const float4*)src + (size_t)i * 2;
    float4 a = sp[0], b = sp[1];
    u16x8 o;
    o[0] = f2bf(a.x); o[1] = f2bf(a.y); o[2] = f2bf(a.z); o[3] = f2bf(a.w);
    o[4] = f2bf(b.x); o[5] = f2bf(b.y); o[6] = f2bf(b.z); o[7] = f2bf(b.w);
    *((u16x8*)dst + i) = o;
  }
}

// ------------------------------------------------------------------- GEMM
// C[M][N] = A[M][K] * B[N][K]^T + bias[N].  (unchanged)
template <int OUT_BF16>
__global__ __launch_bounds__(256) void gemm_bt(const u16* __restrict__ A,
                                               const u16* __restrict__ B,
                                               const float* __restrict__ bias,
                                               void* __restrict__ Cout, int M,
                                               int N, int K) {
  __shared__ __attribute__((aligned(16))) u16 As[128 * 64];
  __shared__ __attribute__((aligned(16))) u16 Bs[128 * 64];
  const int t = threadIdx.x, lane = t & 63, w = t >> 6;
  const int l15 = lane & 15, l4 = lane >> 4;
  const int bm = blockIdx.x * 128, bn = blockIdx.y * 128;
  const int wr = (w >> 1) * 64, wc = (w & 1) * 64;

  f32x4 z4 = {0.f, 0.f, 0.f, 0.f};
  f32x4 acc[4][4];
#pragma unroll
  for (int i = 0; i < 4; ++i)
#pragma unroll
    for (int j = 0; j < 4; ++j) acc[i][j] = z4;

  const int srow = t >> 3;
  const int scol = ((t & 7) ^ (srow & 7)) << 3;
  const u16* Ag = A + (size_t)(bm + srow) * K + scol;
  const u16* Bg = B + (size_t)(bn + srow) * K + scol;
  u16* AsW = As + w * 512;
  u16* BsW = Bs + w * 512;

  for (int k0 = 0; k0 < K; k0 += 64) {
    __syncthreads();
#pragma unroll
    for (int i = 0; i < 4; ++i) {
      GLDS16(Ag + k0 + i * 32 * K, AsW + i * 2048);
      GLDS16(Bg + k0 + i * 32 * K, BsW + i * 2048);
    }
    __syncthreads();
#pragma unroll
    for (int kc = 0; kc < 2; ++kc) {
      bf16x8 af[4], bf[4];
#pragma unroll
      for (int x = 0; x < 4; ++x) {
        int ra = wr + x * 16 + l15;
        af[x] = *(const bf16x8*)(As + ra * 64 + (((kc * 4 + l4) ^ (ra & 7)) << 3));
        int rb = wc + x * 16 + l15;
        bf[x] = *(const bf16x8*)(Bs + rb * 64 + (((kc * 4 + l4) ^ (rb & 7)) << 3));
      }
#pragma unroll
      for (int mi = 0; mi < 4; ++mi)
#pragma unroll
        for (int ni = 0; ni < 4; ++ni)
          acc[mi][ni] = mfma_bf16(af[mi], bf[ni], acc[mi][ni]);
    }
  }
  const int cr = l4 * 4, cc = l15;
#pragma unroll
  for (int ni = 0; ni < 4; ++ni) {
    int col = bn + wc + ni * 16 + cc;
    float bv = bias[col];
#pragma unroll
    for (int mi = 0; mi < 4; ++mi)
#pragma unroll
      for (int r = 0; r < 4; ++r) {
        int row = bm + wr + mi * 16 + cr + r;
        float v = acc[mi][ni][r] + bv;
        if (OUT_BF16)
          ((u16*)Cout)[(size_t)row * N + col] = f2bf(v);
        else
          ((float*)Cout)[(size_t)row * N + col] = v;
      }
  }
}

// -------------------------------------------------------------- attention
// Vt swizzle: slot ^= (d ^ (d>>3)) & 7 — varies with d&7 (read axis) and
// d>>3 (scatter-write axis): read conflict-free, write 2-way (free).
__device__ __forceinline__ int vt_idx(int d, int kk) {
  int swz = (d ^ (d >> 3)) & 7;
  return d * 64 + ((((kk >> 3) ^ swz) << 3) | (kk & 7));
}
// Ps is wave-private; ~2-way after this swizzle.
__device__ __forceinline__ int ps_idx(int r, int c) {
  return r * 64 + ((((c >> 3) ^ ((r >> 2) & 7)) << 3) | (c & 7));
}

__global__ __launch_bounds__(256) void attn_fwd(const u16* __restrict__ qkv,
                                                u16* __restrict__ ctx) {
  constexpr int NQ = 6144, SD = 2048;
  __shared__ __attribute__((aligned(16))) u16 Ks[2][64 * 128];  // dbuf
  __shared__ __attribute__((aligned(16))) u16 Vt[2][128 * 64];  // dbuf
  __shared__ __attribute__((aligned(16))) u16 Ps[64 * 64];      // wave-private
  const int t = threadIdx.x, lane = t & 63, w = t >> 6;
  const int l15 = lane & 15, l4 = lane >> 4;
  const int h = blockIdx.y, b = blockIdx.z;
  const size_t rowbase = (size_t)b * SD;
  const int hq = h * 384;

  const u16* Kg = qkv + (rowbase + (t >> 4)) * NQ + hq + 128 +
                  (((t & 15) ^ ((t >> 4) & 7)) << 3);
  const u16* Vg = qkv + (rowbase + (t & 15)) * NQ + hq + 256 + ((t >> 4) << 3);
  const int vkk = t & 15, vd0 = (t >> 4) << 3;

  const float C = 0.12751879522447905f;   // (1/sqrt(128)) * log2(e)
  const float THRC = 62.73592239488341f;  // 8 / C (raw-logit defer threshold)

  // two q-tiles per block: (31-bx) heavy + (bx) light -> 33 k-tiles uniform
  for (int seg = 0; seg < 2; ++seg) {
    const int q0 = (seg == 0 ? (31 - (int)blockIdx.x) : (int)blockIdx.x) * 64;
    const int nt = (q0 >> 6) + 1;
    const int qrow = q0 + w * 16 + l4 * 4;  // + r

    bf16x8 qf[4];
    {
      const u16* qp = qkv + (rowbase + q0 + w * 16 + l15) * NQ + hq + l4 * 8;
#pragma unroll
      for (int kc = 0; kc < 4; ++kc) qf[kc] = *(const bf16x8*)(qp + kc * 32);
    }

    f32x4 z4 = {0.f, 0.f, 0.f, 0.f};
    f32x4 oacc[8];
#pragma unroll
    for (int i = 0; i < 8; ++i) oacc[i] = z4;
    float m_run[4], l_run[4];
#pragma unroll
    for (int r = 0; r < 4; ++r) { m_run[r] = -3.0e38f; l_run[r] = 0.f; }

    // ---- prologue: K(0)->Ks[0]; V(0)->regs; scatter; V(1)->regs
    u16x8 vA[4], vB[4];
#pragma unroll
    for (int i = 0; i < 4; ++i)
      GLDS16(Kg + (size_t)(i * 16) * NQ, &Ks[0][i * 2048 + w * 512]);
#pragma unroll
    for (int p = 0; p < 4; ++p)
      vA[p] = *(const u16x8*)(Vg + (size_t)(p * 16) * NQ);
    __syncthreads();  // K(0) landed; prev segment fully done
#pragma unroll
    for (int p = 0; p < 4; ++p) {
      int kk = p * 16 + vkk;
#pragma unroll
      for (int j = 0; j < 8; ++j) Vt[0][vt_idx(vd0 + j, kk)] = vA[p][j];
    }
    {
      const int kv = (nt > 1) ? 64 : 0;
#pragma unroll
      for (int p = 0; p < 4; ++p)
        vA[p] = *(const u16x8*)(Vg + (size_t)(kv + p * 16) * NQ);
    }
    __syncthreads();  // Vt[0] visible to all waves

    // ---- main loop: ONE barrier per tile; K/V prefetch hidden under compute
    for (int tt = 0; tt < nt; ++tt) {
      const int k0 = tt * 64, cur = tt & 1;
      const u16* KsC = &Ks[cur][0];
      u16* KsN = &Ks[cur ^ 1][0];
      const u16* VtC = &Vt[cur][0];
      u16* VtN = &Vt[cur ^ 1][0];

      // issue K(t+1) -> Ks[cur^1]  (clamped; redundant at tail, never read)
      const int kn = (k0 + 64 <= q0) ? k0 + 64 : q0;
#pragma unroll
      for (int i = 0; i < 4; ++i)
        GLDS16(Kg + (size_t)(kn + i * 16) * NQ, KsN + i * 2048 + w * 512);
      // issue V(t+2) -> vB
      const int kv = (k0 + 128 <= q0) ? k0 + 128 : q0;
#pragma unroll
      for (int p = 0; p < 4; ++p)
        vB[p] = *(const u16x8*)(Vg + (size_t)(kv + p * 16) * NQ);

      // S = Q K^T (raw logits)
      f32x4 sc[4];
#pragma unroll
      for (int nf = 0; nf < 4; ++nf) sc[nf] = z4;
#pragma unroll
      for (int kc = 0; kc < 4; ++kc)
#pragma unroll
        for (int nf = 0; nf < 4; ++nf) {
          int rk = nf * 16 + l15;
          bf16x8 kf = *(const bf16x8*)(KsC + rk * 128 +
                                       (((kc * 4 + l4) ^ (rk & 7)) << 3));
          sc[nf] = mfma_bf16(qf[kc], kf, sc[nf]);
        }
      // causal mask: only diagonal tile is partial
      if (k0 == q0) {
#pragma unroll
        for (int nf = 0; nf < 4; ++nf) {
          int col = k0 + nf * 16 + l15;
#pragma unroll
          for (int r = 0; r < 4; ++r)
            if (col > qrow + r) sc[nf][r] = -3.0e38f;
        }
      }
      // row max over 16 col-lanes
      float mx[4];
#pragma unroll
      for (int r = 0; r < 4; ++r)
        mx[r] = fmaxf(fmaxf(sc[0][r], sc[1][r]), fmaxf(sc[2][r], sc[3][r]));
#pragma unroll
      for (int off = 8; off >= 1; off >>= 1)
#pragma unroll
        for (int r = 0; r < 4; ++r)
          mx[r] = fmaxf(mx[r], __shfl_xor(mx[r], off));
      // defer-max rescale
      bool upd = false;
#pragma unroll
      for (int r = 0; r < 4; ++r) upd |= (mx[r] > m_run[r] + THRC);
      if (__any(upd)) {
#pragma unroll
        for (int r = 0; r < 4; ++r) {
          float mn = fmaxf(m_run[r], mx[r]);
          float cr = exp2f((m_run[r] - mn) * C);
          m_run[r] = mn;
          l_run[r] *= cr;
#pragma unroll
          for (int nf = 0; nf < 8; ++nf) oacc[nf][r] *= cr;
        }
      }
      float mC[4], sm[4];
#pragma unroll
      for (int r = 0; r < 4; ++r) mC[r] = m_run[r] * C;
#pragma unroll
      for (int nf = 0; nf < 4; ++nf)
#pragma unroll
        for (int r = 0; r < 4; ++r)
          sc[nf][r] = exp2f(fmaf(sc[nf][r], C, -mC[r]));
#pragma unroll
      for (int r = 0; r < 4; ++r)
        sm[r] = (sc[0][r] + sc[1][r]) + (sc[2][r] + sc[3][r]);
#pragma unroll
      for (int off = 8; off >= 1; off >>= 1)
#pragma unroll
        for (int r = 0; r < 4; ++r) sm[r] += __shfl_xor(sm[r], off);
#pragma unroll
      for (int r = 0; r < 4; ++r) l_run[r] += sm[r];
      // P -> Ps (wave-private rows)
#pragma unroll
      for (int nf = 0; nf < 4; ++nf)
#pragma unroll
        for (int r = 0; r < 4; ++r)
          ((__bf16*)Ps)[ps_idx(w * 16 + l4 * 4 + r, nf * 16 + l15)] =
              (__bf16)sc[nf][r];
      // scatter V(t+1) regs -> Vt[cur^1] (WAR vs PV(t-1) barrier-separated)
#pragma unroll
      for (int p = 0; p < 4; ++p) {
        int kk = p * 16 + vkk;
#pragma unroll
        for (int j = 0; j < 8; ++j) VtN[vt_idx(vd0 + j, kk)] = vA[p][j];
      }
      // O += P V from Vt[cur]
#pragma unroll
      for (int kc = 0; kc < 2; ++kc) {
        bf16x8 pf =
            *(const bf16x8*)(Ps + ps_idx(w * 16 + l15, kc * 32 + l4 * 8));
#pragma unroll
        for (int nf = 0; nf < 8; ++nf) {
          bf16x8 vf =
              *(const bf16x8*)(VtC + vt_idx(nf * 16 + l15, kc * 32 + l4 * 8));
          oacc[nf] = mfma_bf16(pf, vf, oacc[nf]);
        }
      }
      __syncthreads();  // drain K(t+1)/V(t+2); publish scatter; close WARs
#pragma unroll
      for (int p = 0; p < 4; ++p) vA[p] = vB[p];
    }
    // normalize + store ctx
    float inv[4];
#pragma unroll
    for (int r = 0; r < 4; ++r) inv[r] = 1.f / l_run[r];
    u16* cp = ctx + (rowbase + q0 + w * 16 + l4 * 4) * SD + h * 128 + l15;
#pragma unroll
    for (int nf = 0; nf < 8; ++nf)
#pragma unroll
      for (int r = 0; r < 4; ++r)
        ((__bf16*)cp)[(size_t)r * SD + nf * 16] =
            (__bf16)(oacc[nf][r] * inv[r]);
  }
}

// ----------------------------------------------------------------- launch
extern "C" void kernel_launch(void* const* d_in, const int* in_sizes, int n_in,
                              void* d_out, int out_size, void* d_ws,
                              size_t ws_size, hipStream_t stream) {
  const float* x = (const float*)d_in[0];
  const float* wqkv = (const float*)d_in[2];
  const float* bqkv = (const float*)d_in[3];
  const float* wout = (const float*)d_in[4];
  const float* bout = (const float*)d_in[5];
  float* out = (float*)d_out;
  char* ws = (char*)d_ws;

  u16* xb = (u16*)(ws);                  //  33,554,432  x bf16 (later: ctx)
  u16* wqkvb = (u16*)(ws + 33554432);    //  25,165,824  w_qkv bf16
  u16* woutb = (u16*)(ws + 58720256);    //   8,388,608  w_out bf16
  u16* qkvb = (u16*)(ws + 67108864);     // 100,663,296  qkv bf16
  u16* ctx = xb;                         // reuse (x dead after gemm1)

  cvt_f32_bf16<<<2048, 256, 0, stream>>>(x, xb, 16777216 / 8);
  cvt_f32_bf16<<<2048, 256, 0, stream>>>(wqkv, wqkvb, 12582912 / 8);
  cvt_f32_bf16<<<1024, 256, 0, stream>>>(wout, woutb, 4194304 / 8);
  gemm_bt<1><<<dim3(64, 48), 256, 0, stream>>>(xb, wqkvb, bqkv, qkvb, 8192,
                                               6144, 2048);
  attn_fwd<<<dim3(16, 16, 4), 256, 0, stream>>>(qkvb, ctx);
  gemm_bt<0><<<dim3(64, 16), 256, 0, stream>>>(ctx, woutb, bout, out, 8192,
                                               2048, 2048);
}

// Round 5
// 688.424 us; speedup vs baseline: 1.1437x; 1.0249x over previous
//
#include <hip/hip_runtime.h>

typedef unsigned short u16;
typedef __bf16 bf16x8 __attribute__((ext_vector_type(8)));
typedef unsigned short u16x8 __attribute__((ext_vector_type(8)));
typedef float f32x4 __attribute__((ext_vector_type(4)));

#define GLDS16(gp, lp)                                                        \
  __builtin_amdgcn_global_load_lds(                                           \
      (const __attribute__((address_space(1))) void*)(gp),                    \
      (__attribute__((address_space(3))) void*)(lp), 16, 0, 0)

__device__ __forceinline__ u16 f2bf(float f) {
  unsigned u = __float_as_uint(f);
  u += 0x7FFFu + ((u >> 16) & 1u);
  return (u16)(u >> 16);
}

__device__ __forceinline__ f32x4 mfma_bf16(bf16x8 a, bf16x8 b, f32x4 c) {
  return __builtin_amdgcn_mfma_f32_16x16x32_bf16(a, b, c, 0, 0, 0);
}

// ---------------------------------------------------------------- convert
__global__ void cvt_f32_bf16(const float* __restrict__ src,
                             u16* __restrict__ dst, int n8) {
  for (int i = blockIdx.x * blockDim.x + threadIdx.x; i < n8;
       i += gridDim.x * blockDim.x) {
    const float4* sp = (const float4*)src + (size_t)i * 2;
    float4 a = sp[0], b = sp[1];
    u16x8 o;
    o[0] = f2bf(a.x); o[1] = f2bf(a.y); o[2] = f2bf(a.z); o[3] = f2bf(a.w);
    o[4] = f2bf(b.x); o[5] = f2bf(b.y); o[6] = f2bf(b.z); o[7] = f2bf(b.w);
    *((u16x8*)dst + i) = o;
  }
}

// ------------------------------------------------------------------- GEMM
// C[M][N] = A[M][K] * B[N][K]^T + bias[N].  (unchanged, proven)
template <int OUT_BF16>
__global__ __launch_bounds__(256) void gemm_bt(const u16* __restrict__ A,
                                               const u16* __restrict__ B,
                                               const float* __restrict__ bias,
                                               void* __restrict__ Cout, int M,
                                               int N, int K) {
  __shared__ __attribute__((aligned(16))) u16 As[128 * 64];
  __shared__ __attribute__((aligned(16))) u16 Bs[128 * 64];
  const int t = threadIdx.x, lane = t & 63, w = t >> 6;
  const int l15 = lane & 15, l4 = lane >> 4;
  const int bm = blockIdx.x * 128, bn = blockIdx.y * 128;
  const int wr = (w >> 1) * 64, wc = (w & 1) * 64;

  f32x4 z4 = {0.f, 0.f, 0.f, 0.f};
  f32x4 acc[4][4];
#pragma unroll
  for (int i = 0; i < 4; ++i)
#pragma unroll
    for (int j = 0; j < 4; ++j) acc[i][j] = z4;

  const int srow = t >> 3;
  const int scol = ((t & 7) ^ (srow & 7)) << 3;
  const u16* Ag = A + (size_t)(bm + srow) * K + scol;
  const u16* Bg = B + (size_t)(bn + srow) * K + scol;
  u16* AsW = As + w * 512;
  u16* BsW = Bs + w * 512;

  for (int k0 = 0; k0 < K; k0 += 64) {
    __syncthreads();
#pragma unroll
    for (int i = 0; i < 4; ++i) {
      GLDS16(Ag + k0 + i * 32 * K, AsW + i * 2048);
      GLDS16(Bg + k0 + i * 32 * K, BsW + i * 2048);
    }
    __syncthreads();
#pragma unroll
    for (int kc = 0; kc < 2; ++kc) {
      bf16x8 af[4], bf[4];
#pragma unroll
      for (int x = 0; x < 4; ++x) {
        int ra = wr + x * 16 + l15;
        af[x] = *(const bf16x8*)(As + ra * 64 + (((kc * 4 + l4) ^ (ra & 7)) << 3));
        int rb = wc + x * 16 + l15;
        bf[x] = *(const bf16x8*)(Bs + rb * 64 + (((kc * 4 + l4) ^ (rb & 7)) << 3));
      }
#pragma unroll
      for (int mi = 0; mi < 4; ++mi)
#pragma unroll
        for (int ni = 0; ni < 4; ++ni)
          acc[mi][ni] = mfma_bf16(af[mi], bf[ni], acc[mi][ni]);
    }
  }
  const int cr = l4 * 4, cc = l15;
#pragma unroll
  for (int ni = 0; ni < 4; ++ni) {
    int col = bn + wc + ni * 16 + cc;
    float bv = bias[col];
#pragma unroll
    for (int mi = 0; mi < 4; ++mi)
#pragma unroll
      for (int r = 0; r < 4; ++r) {
        int row = bm + wr + mi * 16 + cr + r;
        float v = acc[mi][ni][r] + bv;
        if (OUT_BF16)
          ((u16*)Cout)[(size_t)row * N + col] = f2bf(v);
        else
          ((float*)Cout)[(size_t)row * N + col] = v;
      }
  }
}

// -------------------------------------------------------------- attention
// Vt swizzle (round-2 proven): read conflict-free, scatter-write 2-way.
__device__ __forceinline__ int vt_idx(int d, int kk) {
  int swz = (d ^ (d >> 3)) & 7;
  return d * 64 + ((((kk >> 3) ^ swz) << 3) | (kk & 7));
}
__device__ __forceinline__ int ps_idx(int r, int c) {
  return r * 64 + ((((c >> 3) ^ ((r >> 2) & 7)) << 3) | (c & 7));
}

// Block: 4 waves x 32 q-rows = 128 q-rows.  K via GLDS (XOR-swizzled),
// V via reg ping-pong + swizzled scatter (proven round-2 path).
__global__ __launch_bounds__(256, 2) void attn_fwd(const u16* __restrict__ qkv,
                                                   u16* __restrict__ ctx) {
  constexpr int NQ = 6144, SD = 2048;
  __shared__ __attribute__((aligned(16))) u16 Ks[2][64 * 128];
  __shared__ __attribute__((aligned(16))) u16 Vt[2][128 * 64];
  __shared__ __attribute__((aligned(16))) u16 Ps[128 * 64];
  const int t = threadIdx.x, lane = t & 63, w = t >> 6;
  const int l15 = lane & 15, l4 = lane >> 4;
  const int h = blockIdx.y, b = blockIdx.z;
  const size_t rowbase = (size_t)b * 2048;
  const int hq = h * 384;

  const u16* Kg = qkv + (rowbase + (t >> 4)) * NQ + hq + 128 +
                  (((t & 15) ^ ((t >> 4) & 7)) << 3);
  const u16* Vg = qkv + (rowbase + (t & 15)) * NQ + hq + 256 + ((t >> 4) << 3);
  const int vkk = t & 15, vd0 = (t >> 4) << 3;

  const float C = 0.12751879522447905f;   // (1/sqrt(128)) * log2(e)
  const float THRC = 62.73592239488341f;  // 8 / C

  for (int seg = 0; seg < 2; ++seg) {
    const int qt = (seg == 0) ? (15 - (int)blockIdx.x) : (int)blockIdx.x;
    const int q0 = qt * 128;
    const int nt = 2 * qt + 2;
    const int qr0 = q0 + w * 32 + l4 * 4;  // + mi*16 + r

    bf16x8 qf[2][4];
#pragma unroll
    for (int mi = 0; mi < 2; ++mi) {
      const u16* qp =
          qkv + (rowbase + q0 + w * 32 + mi * 16 + l15) * NQ + hq + l4 * 8;
#pragma unroll
      for (int kc = 0; kc < 4; ++kc) qf[mi][kc] = *(const bf16x8*)(qp + kc * 32);
    }

    f32x4 z4 = {0.f, 0.f, 0.f, 0.f};
    f32x4 oacc[2][8];
#pragma unroll
    for (int mi = 0; mi < 2; ++mi)
#pragma unroll
      for (int i = 0; i < 8; ++i) oacc[mi][i] = z4;
    float m_run[2][4], l_run[2][4];
#pragma unroll
    for (int mi = 0; mi < 2; ++mi)
#pragma unroll
      for (int r = 0; r < 4; ++r) { m_run[mi][r] = -3.0e38f; l_run[mi][r] = 0.f; }

    // ---- prologue: K(0)->Ks[0]; V(0)->regs; scatter->Vt[0]; V(1)->regs
    u16x8 vA[4], vB[4];
#pragma unroll
    for (int i = 0; i < 4; ++i)
      GLDS16(Kg + (size_t)(i * 16) * NQ, &Ks[0][i * 2048 + w * 512]);
#pragma unroll
    for (int p = 0; p < 4; ++p)
      vA[p] = *(const u16x8*)(Vg + (size_t)(p * 16) * NQ);
    __syncthreads();  // K(0) landed; previous segment's LDS reads done
#pragma unroll
    for (int p = 0; p < 4; ++p) {
      int kk = p * 16 + vkk;
#pragma unroll
      for (int j = 0; j < 8; ++j) Vt[0][vt_idx(vd0 + j, kk)] = vA[p][j];
    }
#pragma unroll
    for (int p = 0; p < 4; ++p)
      vA[p] = *(const u16x8*)(Vg + (size_t)(64 + p * 16) * NQ);
    __syncthreads();  // Vt[0] visible to all waves

    for (int tt = 0; tt < nt; ++tt) {
      const int k0 = tt * 64, cur = tt & 1;
      // prefetch K(t+1) -> Ks[cur^1] (clamped; tail loads redundant, in-bounds)
      const int kn = (k0 + 64 < q0 + 64) ? k0 + 64 : q0 + 64;
#pragma unroll
      for (int i = 0; i < 4; ++i)
        GLDS16(Kg + (size_t)(kn + i * 16) * NQ,
               &Ks[cur ^ 1][i * 2048 + w * 512]);
      // prefetch V(t+2) -> vB
      const int kv = (k0 + 128 < q0 + 64) ? k0 + 128 : q0 + 64;
#pragma unroll
      for (int p = 0; p < 4; ++p)
        vB[p] = *(const u16x8*)(Vg + (size_t)(kv + p * 16) * NQ);

      // S = Q K^T
      f32x4 sc[2][4];
#pragma unroll
      for (int mi = 0; mi < 2; ++mi)
#pragma unroll
        for (int nf = 0; nf < 4; ++nf) sc[mi][nf] = z4;
#pragma unroll
      for (int kc = 0; kc < 4; ++kc)
#pragma unroll
        for (int nf = 0; nf < 4; ++nf) {
          int rk = nf * 16 + l15;
          bf16x8 kf = *(const bf16x8*)(&Ks[cur][rk * 128 +
                                              (((kc * 4 + l4) ^ (rk & 7)) << 3)]);
          sc[0][nf] = mfma_bf16(qf[0][kc], kf, sc[0][nf]);
          sc[1][nf] = mfma_bf16(qf[1][kc], kf, sc[1][nf]);
        }
      // causal mask: only last two tiles are partial
      if (tt + 2 >= nt) {
#pragma unroll
        for (int mi = 0; mi < 2; ++mi)
#pragma unroll
          for (int nf = 0; nf < 4; ++nf) {
            int col = k0 + nf * 16 + l15;
            int qr = qr0 + mi * 16;
#pragma unroll
            for (int r = 0; r < 4; ++r)
              if (col > qr + r) sc[mi][nf][r] = -3.0e38f;
          }
      }
      // row max over 16 col-lanes
      float mx[2][4];
#pragma unroll
      for (int mi = 0; mi < 2; ++mi)
#pragma unroll
        for (int r = 0; r < 4; ++r)
          mx[mi][r] = fmaxf(fmaxf(sc[mi][0][r], sc[mi][1][r]),
                            fmaxf(sc[mi][2][r], sc[mi][3][r]));
#pragma unroll
      for (int off = 8; off >= 1; off >>= 1)
#pragma unroll
        for (int mi = 0; mi < 2; ++mi)
#pragma unroll
          for (int r = 0; r < 4; ++r)
            mx[mi][r] = fmaxf(mx[mi][r], __shfl_xor(mx[mi][r], off));
      // defer-max rescale
      bool upd = false;
#pragma unroll
      for (int mi = 0; mi < 2; ++mi)
#pragma unroll
        for (int r = 0; r < 4; ++r)
          upd |= (mx[mi][r] > m_run[mi][r] + THRC);
      if (__any(upd)) {
#pragma unroll
        for (int mi = 0; mi < 2; ++mi)
#pragma unroll
          for (int r = 0; r < 4; ++r) {
            float mn = fmaxf(m_run[mi][r], mx[mi][r]);
            float cr = exp2f((m_run[mi][r] - mn) * C);
            m_run[mi][r] = mn;
            l_run[mi][r] *= cr;
#pragma unroll
            for (int nf = 0; nf < 8; ++nf) oacc[mi][nf][r] *= cr;
          }
      }
      // P = exp2(S*C - m*C); row sums; Ps writes
#pragma unroll
      for (int mi = 0; mi < 2; ++mi) {
        float mC[4], sm[4];
#pragma unroll
        for (int r = 0; r < 4; ++r) mC[r] = m_run[mi][r] * C;
#pragma unroll
        for (int nf = 0; nf < 4; ++nf)
#pragma unroll
          for (int r = 0; r < 4; ++r)
            sc[mi][nf][r] = exp2f(fmaf(sc[mi][nf][r], C, -mC[r]));
#pragma unroll
        for (int r = 0; r < 4; ++r)
          sm[r] = (sc[mi][0][r] + sc[mi][1][r]) + (sc[mi][2][r] + sc[mi][3][r]);
#pragma unroll
        for (int off = 8; off >= 1; off >>= 1)
#pragma unroll
          for (int r = 0; r < 4; ++r) sm[r] += __shfl_xor(sm[r], off);
#pragma unroll
        for (int r = 0; r < 4; ++r) l_run[mi][r] += sm[r];
#pragma unroll
        for (int nf = 0; nf < 4; ++nf)
#pragma unroll
          for (int r = 0; r < 4; ++r)
            ((__bf16*)Ps)[ps_idx(w * 32 + mi * 16 + l4 * 4 + r,
                                 nf * 16 + l15)] = (__bf16)sc[mi][nf][r];
      }
      // scatter V(t+1) -> Vt[cur^1] (WAR closed by barrier at end of t-1)
#pragma unroll
      for (int p = 0; p < 4; ++p) {
        int kk = p * 16 + vkk;
#pragma unroll
        for (int j = 0; j < 8; ++j) Vt[cur ^ 1][vt_idx(vd0 + j, kk)] = vA[p][j];
      }
      // O += P V from Vt[cur]
#pragma unroll
      for (int kc = 0; kc < 2; ++kc) {
        bf16x8 pf0 =
            *(const bf16x8*)(Ps + ps_idx(w * 32 + l15, kc * 32 + l4 * 8));
        bf16x8 pf1 =
            *(const bf16x8*)(Ps + ps_idx(w * 32 + 16 + l15, kc * 32 + l4 * 8));
#pragma unroll
        for (int nf = 0; nf < 8; ++nf) {
          bf16x8 vf = *(const bf16x8*)(&Vt[cur][vt_idx(nf * 16 + l15,
                                                       kc * 32 + l4 * 8)]);
          oacc[0][nf] = mfma_bf16(pf0, vf, oacc[0][nf]);
          oacc[1][nf] = mfma_bf16(pf1, vf, oacc[1][nf]);
        }
      }
      __syncthreads();  // drain prefetches; publish scatter; close WARs
#pragma unroll
      for (int p = 0; p < 4; ++p) vA[p] = vB[p];
    }
    // normalize + store
#pragma unroll
    for (int mi = 0; mi < 2; ++mi) {
      float inv[4];
#pragma unroll
      for (int r = 0; r < 4; ++r) inv[r] = 1.f / l_run[mi][r];
      u16* cp = ctx + (rowbase + q0 + w * 32 + mi * 16 + l4 * 4) * SD +
                h * 128 + l15;
#pragma unroll
      for (int nf = 0; nf < 8; ++nf)
#pragma unroll
        for (int r = 0; r < 4; ++r)
          ((__bf16*)cp)[(size_t)r * SD + nf * 16] =
              (__bf16)(oacc[mi][nf][r] * inv[r]);
    }
  }
}

// ----------------------------------------------------------------- launch
extern "C" void kernel_launch(void* const* d_in, const int* in_sizes, int n_in,
                              void* d_out, int out_size, void* d_ws,
                              size_t ws_size, hipStream_t stream) {
  const float* x = (const float*)d_in[0];
  const float* wqkv = (const float*)d_in[2];
  const float* bqkv = (const float*)d_in[3];
  const float* wout = (const float*)d_in[4];
  const float* bout = (const float*)d_in[5];
  float* out = (float*)d_out;
  char* ws = (char*)d_ws;

  u16* xb = (u16*)(ws);                  //  33,554,432  x bf16 (later: ctx)
  u16* wqkvb = (u16*)(ws + 33554432);    //  25,165,824  w_qkv bf16
  u16* woutb = (u16*)(ws + 58720256);    //   8,388,608  w_out bf16
  u16* qkvb = (u16*)(ws + 67108864);     // 100,663,296  qkv bf16
  u16* ctx = xb;                         // reuse (x dead after gemm1)

  cvt_f32_bf16<<<2048, 256, 0, stream>>>(x, xb, 16777216 / 8);
  cvt_f32_bf16<<<2048, 256, 0, stream>>>(wqkv, wqkvb, 12582912 / 8);
  cvt_f32_bf16<<<1024, 256, 0, stream>>>(wout, woutb, 4194304 / 8);
  gemm_bt<1><<<dim3(64, 48), 256, 0, stream>>>(xb, wqkvb, bqkv, qkvb, 8192,
                                               6144, 2048);
  attn_fwd<<<dim3(8, 16, 4), 256, 0, stream>>>(qkvb, ctx);
  gemm_bt<0><<<dim3(64, 16), 256, 0, stream>>>(ctx, woutb, bout, out, 8192,
                                               2048, 2048);
}